// Round 7
// baseline (1719.254 us; speedup 1.0000x reference)
//
#include <hip/hip_runtime.h>
#include <math.h>

typedef _Float16 f16;
typedef _Float16 f16x8 __attribute__((ext_vector_type(8)));
typedef float f32x4 __attribute__((ext_vector_type(4)));

// ---------------------------------------------------------------------------
// expand_sum_a: x[b,i] = sum_{s<Sin} src[s*plane + b*KIN + i]  (Sin=1: raw input)
// -> Aexp (rows x KIN*19 fp16)
// planes per row: [0,8K): basis-hi | [8K,16K): basis-lo | xh | xh | xl
// ---------------------------------------------------------------------------
__global__ __launch_bounds__(256) void expand_sum_a(
    const float* __restrict__ src, size_t plane, int Sin,
    f16* __restrict__ Aexp, int KIN, int shift)
{
    int idx = blockIdx.x * 256 + threadIdx.x;
    int i = idx & (KIN - 1);
    int b = idx >> shift;
    float x = 0.0f;
    for (int s = 0; s < Sin; ++s) x += src[(size_t)s * plane + idx];

    float xs = (x + 2.2f) * 2.5f;
    float fj = floorf(xs);
    int jj = (int)fj;
    float t = xs - fj;
    float t2 = t * t, t3 = t2 * t;
    float omt = 1.0f - t;
    float p0 = omt * omt * omt * (1.0f / 6.0f);
    float p1 = (3.0f * t3 - 6.0f * t2 + 4.0f) * (1.0f / 6.0f);
    float p2 = (-3.0f * t3 + 3.0f * t2 + 3.0f * t + 1.0f) * (1.0f / 6.0f);
    float p3 = t3 * (1.0f / 6.0f);

    union { f16 h[8]; uint4 v; } hi, lo;
    bool inr = (jj >= 0 && jj <= 10);
    #pragma unroll
    for (int cc = 0; cc < 8; ++cc) {
        int d = cc - (jj - 3);
        float v = 0.0f;
        if (inr) {
            if (d == 0) v = p0; else if (d == 1) v = p1;
            else if (d == 2) v = p2; else if (d == 3) v = p3;
        }
        f16 h = (f16)v;
        hi.h[cc] = h;
        lo.h[cc] = (f16)(v - (float)h);
    }
    size_t KEXP = (size_t)KIN * 19;
    f16* row = Aexp + (size_t)b * KEXP;
    *(uint4*)(row + (size_t)i * 8) = hi.v;
    *(uint4*)(row + (size_t)KIN * 8 + (size_t)i * 8) = lo.v;
    f16 xh = (f16)x;
    f16 xl = (f16)(x - (float)xh);
    int K16 = KIN * 16;
    row[K16 + i] = xh;
    row[K16 + KIN + i] = xh;
    row[K16 + 2 * KIN + i] = xl;
}

// ---------------------------------------------------------------------------
// prep_b (round-3 verified): planes [qw x8][qw x8][wh][wl][wh]
// pairing with A: (bh+bl)*qw + xh*wh + xh*wl + xl*wh
// ---------------------------------------------------------------------------
__global__ __launch_bounds__(256) void prep_b(
    const float* __restrict__ BW, const float* __restrict__ SW,
    f16* __restrict__ Bexp, int KIN, int shift)
{
    int idx = blockIdx.x * 256 + threadIdx.x;
    int i = idx & (KIN - 1);
    int o = idx >> shift;
    const float* sp = SW + ((size_t)o * KIN + i) * 8;
    union { f16 h[8]; uint4 v; } pk;
    #pragma unroll
    for (int cc = 0; cc < 8; ++cc)
        pk.h[cc] = (f16)(rintf(sp[cc] * 32.0f) * 0.03125f);  // n/32, exact in fp16
    size_t KEXP = (size_t)KIN * 19;
    f16* row = Bexp + (size_t)o * KEXP;
    *(uint4*)(row + (size_t)i * 8) = pk.v;
    *(uint4*)(row + (size_t)KIN * 8 + (size_t)i * 8) = pk.v;
    float w = BW[(size_t)o * KIN + i];
    f16 wh = (f16)w;
    f16 wl = (f16)(w - (float)wh);
    int K16 = KIN * 16;
    row[K16 + i] = wh;
    row[K16 + KIN + i] = wl;
    row[K16 + 2 * KIN + i] = wh;
}

// ---------------------------------------------------------------------------
// gemm_mfma split-K, REGISTER-FRAGMENT version (no LDS, no barriers):
// each wave computes 64x64 of a 128x128 block tile; A/B MFMA fragments are
// loaded straight from row-major global as global_load_dwordx4 (16 rows x 16B
// lines, fully coalesced), ping-pong double-buffered in VGPRs, unroll-2 so no
// register copies. Only sync = compiler's vmcnt before first fragment use
// (~16 MFMAs of slack vs ~200cyc L2 latency). LDS pipe load: zero.
// ---------------------------------------------------------------------------
__global__ __launch_bounds__(256, 3) void gemm_mfma(
    const f16* __restrict__ A, const f16* __restrict__ Bm,
    float* __restrict__ C, int Kfull, int Kc, size_t plane, int N)
{
    const int tid = threadIdx.x;
    const int wave = tid >> 6, lane = tid & 63;
    const int m0 = blockIdx.y * 128, n0 = blockIdx.x * 128;
    const int wm = (wave & 1) * 64, wn = (wave >> 1) * 64;
    const int kb = blockIdx.z * Kc;
    int kcl = Kfull - kb; if (kcl > Kc) kcl = Kc;
    const int nk = kcl >> 5;

    const int lr = lane & 15;            // fragment row within 16
    const int lk = (lane >> 4) * 8;      // fragment k-offset (8 f16 = 16B)

    // 8 per-wave fragment base pointers (4 A rows-groups, 4 B rows-groups)
    const f16* fb[8];
    #pragma unroll
    for (int i = 0; i < 4; ++i) {
        fb[i]     = A  + (size_t)(m0 + wm + i * 16 + lr) * Kfull + kb + lk;
        fb[4 + i] = Bm + (size_t)(n0 + wn + i * 16 + lr) * Kfull + kb + lk;
    }

    f32x4 acc[4][4];
    #pragma unroll
    for (int i = 0; i < 4; ++i)
        #pragma unroll
        for (int j = 0; j < 4; ++j)
            acc[i][j] = (f32x4){0.f, 0.f, 0.f, 0.f};

    f16x8 b0[8], b1[8];
    #pragma unroll
    for (int j = 0; j < 8; ++j) b0[j] = *(const f16x8*)(fb[j]);   // tile 0

    int t = 0;
    while (t + 1 < nk) {
        {   // prefetch tile t+1 into b1
            const int off = (t + 1) << 5;
            #pragma unroll
            for (int j = 0; j < 8; ++j) b1[j] = *(const f16x8*)(fb[j] + off);
        }
        #pragma unroll
        for (int i = 0; i < 4; ++i)
            #pragma unroll
            for (int j = 0; j < 4; ++j)
                acc[i][j] = __builtin_amdgcn_mfma_f32_16x16x32_f16(b0[i], b0[4 + j], acc[i][j], 0, 0, 0);
        if (t + 2 < nk) {   // prefetch tile t+2 into b0
            const int off = (t + 2) << 5;
            #pragma unroll
            for (int j = 0; j < 8; ++j) b0[j] = *(const f16x8*)(fb[j] + off);
        }
        #pragma unroll
        for (int i = 0; i < 4; ++i)
            #pragma unroll
            for (int j = 0; j < 4; ++j)
                acc[i][j] = __builtin_amdgcn_mfma_f32_16x16x32_f16(b1[i], b1[4 + j], acc[i][j], 0, 0, 0);
        t += 2;
    }
    if (t < nk) {   // odd tail: b0 holds tile nk-1
        #pragma unroll
        for (int i = 0; i < 4; ++i)
            #pragma unroll
            for (int j = 0; j < 4; ++j)
                acc[i][j] = __builtin_amdgcn_mfma_f32_16x16x32_f16(b0[i], b0[4 + j], acc[i][j], 0, 0, 0);
    }

    // C/D layout: col=lane&15, row=(lane>>4)*4+reg  [m89-verified]
    float* Cp = C + (size_t)blockIdx.z * plane;
    #pragma unroll
    for (int i = 0; i < 4; ++i) {
        int row = m0 + wm + i * 16 + (lane >> 4) * 4;
        #pragma unroll
        for (int j = 0; j < 4; ++j) {
            int col = n0 + wn + j * 16 + (lane & 15);
            #pragma unroll
            for (int rr = 0; rr < 4; ++rr)
                Cp[(size_t)(row + rr) * N + col] = acc[i][j][rr];
        }
    }
}

// ---------------------------------------------------------------------------
// Fallback fp32 GEMM (round-1 verified, used only if ws_size tiny)
// ---------------------------------------------------------------------------
__global__ __launch_bounds__(256) void kan_gemm(
    const float* __restrict__ X, const float* __restrict__ BW,
    const float* __restrict__ SW, float* __restrict__ Y, int KIN, int OUT)
{
    __shared__ __align__(16) float Asf[72][68];
    __shared__ __align__(16) float Bsf[72][68];
    const int tid = threadIdx.x;
    const int n0 = blockIdx.x * 64;
    const int m0 = blockIdx.y * 64;
    const int tx = tid & 15;
    const int ty = tid >> 4;
    float acc[4][4] = {};
    for (int k0 = 0; k0 < KIN; k0 += 8) {
        #pragma unroll
        for (int rep = 0; rep < 2; ++rep) {
            int idx = rep * 256 + tid;
            int r = idx >> 3, c = idx & 7;
            float x = X[(size_t)(m0 + r) * KIN + k0 + c];
            int bk = c * 9;
            Asf[bk][r] = x;
            #pragma unroll
            for (int z = 0; z < 8; ++z) Asf[bk + 1 + z][r] = 0.0f;
            float xs = (x + 2.2f) * 2.5f;
            float fj = floorf(xs);
            int j = (int)fj;
            if (j >= 0 && j <= 10) {
                float t = xs - fj;
                float t2 = t * t, t3 = t2 * t;
                float omt = 1.0f - t;
                float p0 = omt * omt * omt * (1.0f / 6.0f);
                float p1 = (3.0f * t3 - 6.0f * t2 + 4.0f) * (1.0f / 6.0f);
                float p2 = (-3.0f * t3 + 3.0f * t2 + 3.0f * t + 1.0f) * (1.0f / 6.0f);
                float p3 = t3 * (1.0f / 6.0f);
                if (j >= 3) Asf[bk + 1 + j - 3][r] = p0;
                if (j >= 2 && j <= 9) Asf[bk + 1 + j - 2][r] = p1;
                if (j >= 1 && j <= 8) Asf[bk + 1 + j - 1][r] = p2;
                if (j <= 7) Asf[bk + 1 + j][r] = p3;
            }
        }
        #pragma unroll
        for (int rep = 0; rep < 16; ++rep) {
            int idx = rep * 256 + tid;
            int ol = idx >> 6;
            int l = idx & 63;
            int i = l >> 3, cc = l & 7;
            float v = SW[((size_t)(n0 + ol) * KIN + k0 + i) * 8 + cc];
            Bsf[i * 9 + 1 + cc][ol] = rintf(v * 32.0f) * 0.03125f;
        }
        #pragma unroll
        for (int rep = 0; rep < 2; ++rep) {
            int idx = rep * 256 + tid;
            int ol = idx >> 3, cc = idx & 7;
            Bsf[cc * 9][ol] = BW[(size_t)(n0 + ol) * KIN + k0 + cc];
        }
        __syncthreads();
        #pragma unroll 8
        for (int kk = 0; kk < 72; ++kk) {
            float4 av = *(const float4*)&Asf[kk][ty * 4];
            float4 bv = *(const float4*)&Bsf[kk][tx * 4];
            acc[0][0] += av.x * bv.x; acc[0][1] += av.x * bv.y; acc[0][2] += av.x * bv.z; acc[0][3] += av.x * bv.w;
            acc[1][0] += av.y * bv.x; acc[1][1] += av.y * bv.y; acc[1][2] += av.y * bv.z; acc[1][3] += av.y * bv.w;
            acc[2][0] += av.z * bv.x; acc[2][1] += av.z * bv.y; acc[2][2] += av.z * bv.z; acc[2][3] += av.z * bv.w;
            acc[3][0] += av.w * bv.x; acc[3][1] += av.w * bv.y; acc[3][2] += av.w * bv.z; acc[3][3] += av.w * bv.w;
        }
        __syncthreads();
    }
    #pragma unroll
    for (int i = 0; i < 4; ++i) {
        float4 o = make_float4(acc[i][0], acc[i][1], acc[i][2], acc[i][3]);
        *(float4*)&Y[(size_t)(m0 + ty * 4 + i) * OUT + n0 + tx * 4] = o;
    }
}

// ---------------------------------------------------------------------------
// huxley_rd (round-1 verified core); input = sum of S partial planes.
// ---------------------------------------------------------------------------
__device__ __forceinline__ float block_reduce_sum(float v, float* red, int tid) {
    red[tid] = v; __syncthreads();
    #pragma unroll
    for (int s = 128; s > 0; s >>= 1) {
        if (tid < s) red[tid] += red[tid + s];
        __syncthreads();
    }
    float r = red[0]; __syncthreads();
    return r;
}
__device__ __forceinline__ float block_reduce_min(float v, float* red, int tid) {
    red[tid] = v; __syncthreads();
    #pragma unroll
    for (int s = 128; s > 0; s >>= 1) {
        if (tid < s) red[tid] = fminf(red[tid], red[tid + s]);
        __syncthreads();
    }
    float r = red[0]; __syncthreads();
    return r;
}

__device__ void fft1024(float2* X, const float2* tw, int tid, bool inverse) {
    if (!inverse) {
        for (int sh = 9; sh >= 0; --sh) {
            int h = 1 << sh;
            #pragma unroll
            for (int q = 0; q < 2; ++q) {
                int b = tid + q * 256;
                int g = b >> sh, j = b & (h - 1);
                int i0 = (g << (sh + 1)) + j, i1 = i0 + h;
                float2 u = X[i0], v = X[i1];
                float dx = u.x - v.x, dy = u.y - v.y;
                X[i0] = make_float2(u.x + v.x, u.y + v.y);
                float2 w = tw[j << (9 - sh)];
                X[i1] = make_float2(dx * w.x + dy * w.y, dy * w.x - dx * w.y);
            }
            __syncthreads();
        }
    } else {
        for (int sh = 0; sh <= 9; ++sh) {
            int h = 1 << sh;
            #pragma unroll
            for (int q = 0; q < 2; ++q) {
                int b = tid + q * 256;
                int g = b >> sh, j = b & (h - 1);
                int i0 = (g << (sh + 1)) + j, i1 = i0 + h;
                float2 u = X[i0], v = X[i1];
                float2 w = tw[j << (9 - sh)];
                float tx2 = v.x * w.x - v.y * w.y;
                float ty2 = v.x * w.y + v.y * w.x;
                X[i0] = make_float2(u.x + tx2, u.y + ty2);
                X[i1] = make_float2(u.x - tx2, u.y - ty2);
            }
            __syncthreads();
        }
    }
}

__global__ __launch_bounds__(256) void huxley_kernel(
    const float* __restrict__ Pin, size_t plane, int S,
    float* __restrict__ dst,
    const float* __restrict__ sg, const float* __restrict__ dk,
    const float* __restrict__ pa, const float* __restrict__ pgam,
    const float* __restrict__ ptau, const float* __restrict__ pvel,
    const float* __restrict__ gp, const float* __restrict__ chi)
{
    __shared__ float2 A[1024];
    __shared__ float2 Bb[1024];
    __shared__ float sErg[1024];
    __shared__ float sAbs[516];
    __shared__ float2 tw[512];
    __shared__ float red[256];
    __shared__ float sG[516];

    const int tid = threadIdx.x;
    const int row = blockIdx.x;
    const float* pin = Pin + (size_t)row * 1024;
    float* uo = dst + (size_t)row * 1024;

    for (int m = tid; m < 512; m += 256) {
        float s, c;
        sincosf(6.283185307179586f * (float)m * (1.0f / 1024.0f), &s, &c);
        tw[m] = make_float2(c, s);
    }
    for (int k = tid; k < 513; k += 256)
        sG[k] = 1.0f / (1.0f + expf(-sg[k]));
    for (int i = tid; i < 1024; i += 256) {
        float s = 0.0f;
        for (int ss = 0; ss < S; ++ss) s += pin[(size_t)ss * plane + i];
        A[i] = make_float2(s, 0.0f);
    }
    __syncthreads();

    fft1024(A, tw, tid, false);

    for (int p = tid; p < 1024; p += 256) {
        int k = (int)(__brev((unsigned)p) >> 22);
        int m = (k <= 512) ? k : 1024 - k;
        float g = sG[m] * (1.0f / 1024.0f);
        Bb[p] = make_float2(A[p].x * g, A[p].y * g);
    }
    __syncthreads();
    fft1024(Bb, tw, tid, true);
    for (int i = tid; i < 1024; i += 256) sErg[i] = Bb[i].x;
    __syncthreads();

    const float vv = pvel[0];
    for (int p = tid; p < 1024; p += 256) {
        int k = (int)(__brev((unsigned)p) >> 22);
        int m = (k <= 512) ? k : 1024 - k;
        float omg = 1.0f - sG[m];
        float nx = A[p].x * omg, ny = A[p].y * omg;
        float ang = (k <= 512)
            ? (-6.283185307179586f * vv * (float)k * (1.0f / 1024.0f))
            : (6.283185307179586f * vv * (float)(1024 - k) * (1.0f / 1024.0f));
        float sn, cs;
        sincosf(ang, &sn, &cs);
        float yx = nx * cs - ny * sn;
        float yy = nx * sn + ny * cs;
        if (k < 512)       sAbs[k]   = sqrtf(nx * nx + ny * ny);
        else if (k == 512) sAbs[512] = fabsf(yx);
        Bb[p] = make_float2(yx * (1.0f / 1024.0f), yy * (1.0f / 1024.0f));
    }
    __syncthreads();
    fft1024(Bb, tw, tid, true);

    float loc = 0.0f;
    for (int i = tid; i < 1024; i += 256) { float x = Bb[i].x; loc += x * x; }
    float trc = block_reduce_sum(loc, red, tid);

    loc = 0.0f;
    for (int k = tid; k < 513; k += 256) loc += sAbs[k];
    float mean = block_reduce_sum(loc, red, tid) * (1.0f / 513.0f);

    loc = 0.0f;
    for (int k = tid; k < 513; k += 256) { float d = sAbs[k] - mean; loc += d * d; }
    float varsum = block_reduce_sum(loc, red, tid);

    loc = 3.4e38f;
    for (int k = tid; k < 513; k += 256) loc = fminf(loc, sAbs[k]);
    float lmin = block_reduce_min(loc, red, tid);

    float det_pas = varsum * (1.0f / 512.0f) + 1e-6f;
    float sd = sqrtf(det_pas);
    float denom = 2.0f * sd * sd * sd + 1e-8f;
    float c3 = (3.0f * gp[row] - trc / ptau[0]) / denom;
    c3 = fminf(fmaxf(c3, -0.999f), 0.999f);
    float ph = acosf(c3) * (1.0f / 3.0f);
    float amp = 2.0f * sqrtf(lmin * (1.0f / 3.0f) + 1e-8f);
    float nu = sqrtf(trc);
    float achi = fabsf(chi[row]);
    float cbest = 0.0f, ebest = -1.0f;
    #pragma unroll
    for (int kb = 0; kb < 3; ++kb) {
        float ck = amp * cosf(ph + 2.0943951023931953f * (float)kb) * expf(-achi * (float)kb);
        float ek = fabsf(ck) * nu;
        if (ek > ebest) { ebest = ek; cbest = ck; }
    }

    const float a = pa[0], gm = pgam[0];
    const float k0 = dk[0], k1 = dk[1], k2 = dk[2];
    for (int i = tid; i < 1024; i += 256) {
        float e = sErg[i];
        float l = (i > 0) ? sErg[i - 1] : 0.0f;
        float r = (i < 1023) ? sErg[i + 1] : 0.0f;
        float reac = e * (e - a) * (1.0f - e);
        float diff = k0 * l + k1 * e + k2 * r;
        float un = e + 0.1f * (reac + gm * diff);
        float s = un + cbest * Bb[i].x;
        uo[i] = s / (1.0f + expf(-s));
    }
}

// ---------------------------------------------------------------------------

extern "C" void kernel_launch(void* const* d_in, const int* in_sizes, int n_in,
                              void* d_out, int out_size, void* d_ws, size_t ws_size,
                              hipStream_t stream) {
    const float* c    = (const float*)d_in[0];
    const float* bw0  = (const float*)d_in[1];
    const float* sw0  = (const float*)d_in[2];
    const float* bw1  = (const float*)d_in[3];
    const float* sw1  = (const float*)d_in[4];
    const float* bw2  = (const float*)d_in[5];
    const float* sw2  = (const float*)d_in[6];
    const float* sg   = (const float*)d_in[7];
    const float* dk   = (const float*)d_in[8];
    const float* pa   = (const float*)d_in[9];
    const float* pgam = (const float*)d_in[10];
    const float* ptau = (const float*)d_in[11];
    const float* pvel = (const float*)d_in[12];
    const float* gp   = (const float*)d_in[13];
    const float* chi  = (const float*)d_in[14];

    const int B = 4096, NIN = 512, W = 1024, NOUT = 1024;
    const int KE0 = 19 * NIN, KE1 = 19 * W;
    const size_t MN = (size_t)B * W;
    const size_t BE = (size_t)W * KE1 * 2;      // Bexp bytes (39.85 MB)
    dim3 blk(256);

    // ---- pick (CH, S): target grid = 3 blocks/CU (VGPR-bound occupancy 3) ----
    // {4096,3}: grid 8x32x3 = 768 = exactly 3/CU
    struct Cand { int CH, S; };
    const Cand cands[] = {
        {4096, 3}, {2048, 6}, {2048, 3}, {1024, 6}, {1024, 3},
        {512, 3}, {256, 3}, {128, 2}
    };
    int CH = 0, S = 1;
    for (const auto& cd : cands) {
        size_t need = BE + (size_t)cd.CH * KE1 * 2 + (size_t)cd.S * MN * 4;
        if (need <= ws_size) { CH = cd.CH; S = cd.S; break; }
    }

    if (CH > 0) {
        f16* Bexp = (f16*)d_ws;
        float* P  = (float*)((char*)d_ws + BE);                // S planes of M x N fp32
        f16* Aexp = (f16*)((char*)d_ws + BE + (size_t)S * MN * 4);

        // ceil-split Kc (multiple of 32); kernel clamps last split
        const int Kc0 = ((KE0 / 32 + S - 1) / S) * 32;
        const int Kc1 = ((KE1 / 32 + S - 1) / S) * 32;

        // ---- layer 0: KIN=512 ----
        prep_b<<<(W * NIN) / 256, blk, 0, stream>>>(bw0, sw0, Bexp, NIN, 9);
        for (int r0 = 0; r0 < B; r0 += CH) {
            expand_sum_a<<<(CH * NIN) / 256, blk, 0, stream>>>(
                c + (size_t)r0 * NIN, 0, 1, Aexp, NIN, 9);
            gemm_mfma<<<dim3(W / 128, CH / 128, S), blk, 0, stream>>>(
                Aexp, Bexp, P + (size_t)r0 * W, KE0, Kc0, MN, W);
        }
        // ---- layer 1: KIN=1024 ----
        prep_b<<<(W * W) / 256, blk, 0, stream>>>(bw1, sw1, Bexp, W, 10);
        for (int r0 = 0; r0 < B; r0 += CH) {
            expand_sum_a<<<(CH * W) / 256, blk, 0, stream>>>(
                P + (size_t)r0 * W, MN, S, Aexp, W, 10);
            gemm_mfma<<<dim3(W / 128, CH / 128, S), blk, 0, stream>>>(
                Aexp, Bexp, P + (size_t)r0 * W, KE1, Kc1, MN, W);
        }
        // ---- layer 2 ----
        prep_b<<<(NOUT * W) / 256, blk, 0, stream>>>(bw2, sw2, Bexp, W, 10);
        for (int r0 = 0; r0 < B; r0 += CH) {
            expand_sum_a<<<(CH * W) / 256, blk, 0, stream>>>(
                P + (size_t)r0 * W, MN, S, Aexp, W, 10);
            gemm_mfma<<<dim3(NOUT / 128, CH / 128, S), blk, 0, stream>>>(
                Aexp, Bexp, P + (size_t)r0 * W, KE1, Kc1, MN, NOUT);
        }
        huxley_kernel<<<B, blk, 0, stream>>>(P, MN, S, (float*)d_out,
                                             sg, dk, pa, pgam, ptau, pvel, gp, chi);
    } else {
        // fallback: round-1 fp32 path (needs only 33.6 MB ws)
        float* fx0 = (float*)d_ws;
        float* fx1 = fx0 + (size_t)B * W;
        dim3 g0(W / 64, B / 64);
        kan_gemm<<<g0, blk, 0, stream>>>(c,   bw0, sw0, fx0, NIN, W);
        kan_gemm<<<g0, blk, 0, stream>>>(fx0, bw1, sw1, fx1, W,   W);
        dim3 g2(NOUT / 64, B / 64);
        kan_gemm<<<g2, blk, 0, stream>>>(fx1, bw2, sw2, (float*)d_out, W, NOUT);
        huxley_kernel<<<B, blk, 0, stream>>>((float*)d_out, 0, 1, (float*)d_out,
                                             sg, dk, pa, pgam, ptau, pvel, gp, chi);
    }
}

// Round 8
// 877.568 us; speedup vs baseline: 1.9591x; 1.9591x over previous
//
#include <hip/hip_runtime.h>
#include <math.h>

typedef _Float16 f16;
typedef _Float16 f16x8 __attribute__((ext_vector_type(8)));
typedef float f32x4 __attribute__((ext_vector_type(4)));

// ---------------------------------------------------------------------------
// expand_sum_a: x[b,i] = sum_{s<Sin} src[s*plane + b*KIN + i]  (Sin=1: raw input)
// -> Aexp (rows x KIN*19 fp16)
// planes per row: [0,8K): basis-hi | [8K,16K): basis-lo | xh | xh | xl
// ---------------------------------------------------------------------------
__global__ __launch_bounds__(256) void expand_sum_a(
    const float* __restrict__ src, size_t plane, int Sin,
    f16* __restrict__ Aexp, int KIN, int shift)
{
    int idx = blockIdx.x * 256 + threadIdx.x;
    int i = idx & (KIN - 1);
    int b = idx >> shift;
    float x = 0.0f;
    for (int s = 0; s < Sin; ++s) x += src[(size_t)s * plane + idx];

    float xs = (x + 2.2f) * 2.5f;
    float fj = floorf(xs);
    int jj = (int)fj;
    float t = xs - fj;
    float t2 = t * t, t3 = t2 * t;
    float omt = 1.0f - t;
    float p0 = omt * omt * omt * (1.0f / 6.0f);
    float p1 = (3.0f * t3 - 6.0f * t2 + 4.0f) * (1.0f / 6.0f);
    float p2 = (-3.0f * t3 + 3.0f * t2 + 3.0f * t + 1.0f) * (1.0f / 6.0f);
    float p3 = t3 * (1.0f / 6.0f);

    union { f16 h[8]; uint4 v; } hi, lo;
    bool inr = (jj >= 0 && jj <= 10);
    #pragma unroll
    for (int cc = 0; cc < 8; ++cc) {
        int d = cc - (jj - 3);
        float v = 0.0f;
        if (inr) {
            if (d == 0) v = p0; else if (d == 1) v = p1;
            else if (d == 2) v = p2; else if (d == 3) v = p3;
        }
        f16 h = (f16)v;
        hi.h[cc] = h;
        lo.h[cc] = (f16)(v - (float)h);
    }
    size_t KEXP = (size_t)KIN * 19;
    f16* row = Aexp + (size_t)b * KEXP;
    *(uint4*)(row + (size_t)i * 8) = hi.v;
    *(uint4*)(row + (size_t)KIN * 8 + (size_t)i * 8) = lo.v;
    f16 xh = (f16)x;
    f16 xl = (f16)(x - (float)xh);
    int K16 = KIN * 16;
    row[K16 + i] = xh;
    row[K16 + KIN + i] = xh;
    row[K16 + 2 * KIN + i] = xl;
}

// ---------------------------------------------------------------------------
// prep_b (round-3 verified): planes [qw x8][qw x8][wh][wl][wh]
// pairing with A: (bh+bl)*qw + xh*wh + xh*wl + xl*wh
// ---------------------------------------------------------------------------
__global__ __launch_bounds__(256) void prep_b(
    const float* __restrict__ BW, const float* __restrict__ SW,
    f16* __restrict__ Bexp, int KIN, int shift)
{
    int idx = blockIdx.x * 256 + threadIdx.x;
    int i = idx & (KIN - 1);
    int o = idx >> shift;
    const float* sp = SW + ((size_t)o * KIN + i) * 8;
    union { f16 h[8]; uint4 v; } pk;
    #pragma unroll
    for (int cc = 0; cc < 8; ++cc)
        pk.h[cc] = (f16)(rintf(sp[cc] * 32.0f) * 0.03125f);  // n/32, exact in fp16
    size_t KEXP = (size_t)KIN * 19;
    f16* row = Bexp + (size_t)o * KEXP;
    *(uint4*)(row + (size_t)i * 8) = pk.v;
    *(uint4*)(row + (size_t)KIN * 8 + (size_t)i * 8) = pk.v;
    float w = BW[(size_t)o * KIN + i];
    f16 wh = (f16)w;
    f16 wl = (f16)(w - (float)wh);
    int K16 = KIN * 16;
    row[K16 + i] = wh;
    row[K16 + KIN + i] = wl;
    row[K16 + 2 * KIN + i] = wh;
}

// ---------------------------------------------------------------------------
// gemm_mfma split-K, 256x128 block tile, 4 waves each 128x64 (8x4 of 16x16x32),
// 3-stage LDS ring + fine s_waitcnt vmcnt(6) across raw s_barrier (R6-verified
// pipeline), plus XOR bank-swizzle:
//   LDS slot (row, kc16B) holds global (row, kc ^ ((row>>1)&3)).
//   - staging write: lane-contiguous (conflict-free), per-lane GLOBAL source
//     permuted: kc_src = (lane&3) ^ ((lane>>3)&3)
//   - fragment read: kc_read = (lane>>4) ^ (((lane&15)>>1)&3) -> 2 lanes/bank
//     group = conflict-free (m136: 2-way is free)
// ---------------------------------------------------------------------------
__global__ __launch_bounds__(256, 2) void gemm_mfma(
    const f16* __restrict__ A, const f16* __restrict__ Bm,
    float* __restrict__ C, int Kfull, int Kc, size_t plane, int N)
{
    __shared__ f16 As[3][8192];   // [stage][256 rows x 32 k], 64B rows
    __shared__ f16 Bs[3][4096];   // [stage][128 rows x 32 k]

    const int tid = threadIdx.x;
    const int wave = tid >> 6, lane = tid & 63;
    const int m0 = blockIdx.y * 256, n0 = blockIdx.x * 128;
    const int wm = (wave & 1) * 128, wn = (wave >> 1) * 64;
    const int kb = blockIdx.z * Kc;
    int kcl = Kfull - kb; if (kcl > Kc) kcl = Kc;
    const int nk = kcl >> 5;

    // staging: 24 chunks of 1KB (A:0..15, B:16..23); wave handles 6 chunks.
    // per-lane source k-chunk swizzled so LDS ends up in XOR layout.
    const int kc_src = (lane & 3) ^ ((lane >> 3) & 3);
    const f16* gbase[6];
    int isA[6], coff[6];
    #pragma unroll
    for (int j = 0; j < 6; ++j) {
        int cch = wave * 6 + j;
        int a = (cch < 16);
        int c8 = a ? cch : (cch - 16);
        int row0 = (a ? m0 : n0) + c8 * 16 + (lane >> 2);
        gbase[j] = (a ? A : Bm) + (size_t)row0 * Kfull + kb + kc_src * 8;
        isA[j] = a;
        coff[j] = c8 * 512;
    }

    f32x4 acc[8][4];
    #pragma unroll
    for (int i = 0; i < 8; ++i)
        #pragma unroll
        for (int j = 0; j < 4; ++j)
            acc[i][j] = (f32x4){0.f, 0.f, 0.f, 0.f};

    // prologue: tiles 0,1 into stages 0,1
    #pragma unroll
    for (int s = 0; s < 2; ++s) {
        if (s < nk) {
            int k0 = s << 5;
            #pragma unroll
            for (int j = 0; j < 6; ++j) {
                f16* dp = isA[j] ? &As[s][coff[j]] : &Bs[s][coff[j]];
                __builtin_amdgcn_global_load_lds(
                    (const __attribute__((address_space(1))) unsigned int*)(gbase[j] + k0),
                    (__attribute__((address_space(3))) unsigned int*)dp, 16, 0, 0);
            }
        }
    }

    const int lr = lane & 15;
    const int ko = (((lane >> 4) ^ (lr >> 1)) & 3) * 8;   // swizzled k-offset (f16)

    int st = 0;
    for (int t = 0; t < nk; ++t) {
        // drain only tile t's 6 loads; tile t+1's stay in flight
        if (t == nk - 1) asm volatile("s_waitcnt vmcnt(0)" ::: "memory");
        else             asm volatile("s_waitcnt vmcnt(6)" ::: "memory");
        __builtin_amdgcn_s_barrier();
        asm volatile("" ::: "memory");

        if (t + 2 < nk) {
            int k0 = (t + 2) << 5;
            int ns = st + 2; if (ns >= 3) ns -= 3;
            #pragma unroll
            for (int j = 0; j < 6; ++j) {
                f16* dp = isA[j] ? &As[ns][coff[j]] : &Bs[ns][coff[j]];
                __builtin_amdgcn_global_load_lds(
                    (const __attribute__((address_space(1))) unsigned int*)(gbase[j] + k0),
                    (__attribute__((address_space(3))) unsigned int*)dp, 16, 0, 0);
            }
        }

        f16x8 af[8], bf[4];
        #pragma unroll
        for (int i = 0; i < 8; ++i)
            af[i] = *(const f16x8*)&As[st][(wm + i * 16 + lr) * 32 + ko];
        #pragma unroll
        for (int j = 0; j < 4; ++j)
            bf[j] = *(const f16x8*)&Bs[st][(wn + j * 16 + lr) * 32 + ko];
        #pragma unroll
        for (int i = 0; i < 8; ++i)
            #pragma unroll
            for (int j = 0; j < 4; ++j)
                acc[i][j] = __builtin_amdgcn_mfma_f32_16x16x32_f16(af[i], bf[j], acc[i][j], 0, 0, 0);

        if (++st == 3) st = 0;
    }

    // C/D layout: col=lane&15, row=(lane>>4)*4+reg  [m89-verified]
    float* Cp = C + (size_t)blockIdx.z * plane;
    #pragma unroll
    for (int i = 0; i < 8; ++i) {
        int row = m0 + wm + i * 16 + (lane >> 4) * 4;
        #pragma unroll
        for (int j = 0; j < 4; ++j) {
            int col = n0 + wn + j * 16 + lr;
            #pragma unroll
            for (int rr = 0; rr < 4; ++rr)
                Cp[(size_t)(row + rr) * N + col] = acc[i][j][rr];
        }
    }
}

// ---------------------------------------------------------------------------
// Fallback fp32 GEMM (round-1 verified, used only if ws_size tiny)
// ---------------------------------------------------------------------------
__global__ __launch_bounds__(256) void kan_gemm(
    const float* __restrict__ X, const float* __restrict__ BW,
    const float* __restrict__ SW, float* __restrict__ Y, int KIN, int OUT)
{
    __shared__ __align__(16) float Asf[72][68];
    __shared__ __align__(16) float Bsf[72][68];
    const int tid = threadIdx.x;
    const int n0 = blockIdx.x * 64;
    const int m0 = blockIdx.y * 64;
    const int tx = tid & 15;
    const int ty = tid >> 4;
    float acc[4][4] = {};
    for (int k0 = 0; k0 < KIN; k0 += 8) {
        #pragma unroll
        for (int rep = 0; rep < 2; ++rep) {
            int idx = rep * 256 + tid;
            int r = idx >> 3, c = idx & 7;
            float x = X[(size_t)(m0 + r) * KIN + k0 + c];
            int bk = c * 9;
            Asf[bk][r] = x;
            #pragma unroll
            for (int z = 0; z < 8; ++z) Asf[bk + 1 + z][r] = 0.0f;
            float xs = (x + 2.2f) * 2.5f;
            float fj = floorf(xs);
            int j = (int)fj;
            if (j >= 0 && j <= 10) {
                float t = xs - fj;
                float t2 = t * t, t3 = t2 * t;
                float omt = 1.0f - t;
                float p0 = omt * omt * omt * (1.0f / 6.0f);
                float p1 = (3.0f * t3 - 6.0f * t2 + 4.0f) * (1.0f / 6.0f);
                float p2 = (-3.0f * t3 + 3.0f * t2 + 3.0f * t + 1.0f) * (1.0f / 6.0f);
                float p3 = t3 * (1.0f / 6.0f);
                if (j >= 3) Asf[bk + 1 + j - 3][r] = p0;
                if (j >= 2 && j <= 9) Asf[bk + 1 + j - 2][r] = p1;
                if (j >= 1 && j <= 8) Asf[bk + 1 + j - 1][r] = p2;
                if (j <= 7) Asf[bk + 1 + j][r] = p3;
            }
        }
        #pragma unroll
        for (int rep = 0; rep < 16; ++rep) {
            int idx = rep * 256 + tid;
            int ol = idx >> 6;
            int l = idx & 63;
            int i = l >> 3, cc = l & 7;
            float v = SW[((size_t)(n0 + ol) * KIN + k0 + i) * 8 + cc];
            Bsf[i * 9 + 1 + cc][ol] = rintf(v * 32.0f) * 0.03125f;
        }
        #pragma unroll
        for (int rep = 0; rep < 2; ++rep) {
            int idx = rep * 256 + tid;
            int ol = idx >> 3, cc = idx & 7;
            Bsf[cc * 9][ol] = BW[(size_t)(n0 + ol) * KIN + k0 + cc];
        }
        __syncthreads();
        #pragma unroll 8
        for (int kk = 0; kk < 72; ++kk) {
            float4 av = *(const float4*)&Asf[kk][ty * 4];
            float4 bv = *(const float4*)&Bsf[kk][tx * 4];
            acc[0][0] += av.x * bv.x; acc[0][1] += av.x * bv.y; acc[0][2] += av.x * bv.z; acc[0][3] += av.x * bv.w;
            acc[1][0] += av.y * bv.x; acc[1][1] += av.y * bv.y; acc[1][2] += av.y * bv.z; acc[1][3] += av.y * bv.w;
            acc[2][0] += av.z * bv.x; acc[2][1] += av.z * bv.y; acc[2][2] += av.z * bv.z; acc[2][3] += av.z * bv.w;
            acc[3][0] += av.w * bv.x; acc[3][1] += av.w * bv.y; acc[3][2] += av.w * bv.z; acc[3][3] += av.w * bv.w;
        }
        __syncthreads();
    }
    #pragma unroll
    for (int i = 0; i < 4; ++i) {
        float4 o = make_float4(acc[i][0], acc[i][1], acc[i][2], acc[i][3]);
        *(float4*)&Y[(size_t)(m0 + ty * 4 + i) * OUT + n0 + tx * 4] = o;
    }
}

// ---------------------------------------------------------------------------
// huxley_rd (round-1 verified core); input = sum of S partial planes.
// ---------------------------------------------------------------------------
__device__ __forceinline__ float block_reduce_sum(float v, float* red, int tid) {
    red[tid] = v; __syncthreads();
    #pragma unroll
    for (int s = 128; s > 0; s >>= 1) {
        if (tid < s) red[tid] += red[tid + s];
        __syncthreads();
    }
    float r = red[0]; __syncthreads();
    return r;
}
__device__ __forceinline__ float block_reduce_min(float v, float* red, int tid) {
    red[tid] = v; __syncthreads();
    #pragma unroll
    for (int s = 128; s > 0; s >>= 1) {
        if (tid < s) red[tid] = fminf(red[tid], red[tid + s]);
        __syncthreads();
    }
    float r = red[0]; __syncthreads();
    return r;
}

__device__ void fft1024(float2* X, const float2* tw, int tid, bool inverse) {
    if (!inverse) {
        for (int sh = 9; sh >= 0; --sh) {
            int h = 1 << sh;
            #pragma unroll
            for (int q = 0; q < 2; ++q) {
                int b = tid + q * 256;
                int g = b >> sh, j = b & (h - 1);
                int i0 = (g << (sh + 1)) + j, i1 = i0 + h;
                float2 u = X[i0], v = X[i1];
                float dx = u.x - v.x, dy = u.y - v.y;
                X[i0] = make_float2(u.x + v.x, u.y + v.y);
                float2 w = tw[j << (9 - sh)];
                X[i1] = make_float2(dx * w.x + dy * w.y, dy * w.x - dx * w.y);
            }
            __syncthreads();
        }
    } else {
        for (int sh = 0; sh <= 9; ++sh) {
            int h = 1 << sh;
            #pragma unroll
            for (int q = 0; q < 2; ++q) {
                int b = tid + q * 256;
                int g = b >> sh, j = b & (h - 1);
                int i0 = (g << (sh + 1)) + j, i1 = i0 + h;
                float2 u = X[i0], v = X[i1];
                float2 w = tw[j << (9 - sh)];
                float tx2 = v.x * w.x - v.y * w.y;
                float ty2 = v.x * w.y + v.y * w.x;
                X[i0] = make_float2(u.x + tx2, u.y + ty2);
                X[i1] = make_float2(u.x - tx2, u.y - ty2);
            }
            __syncthreads();
        }
    }
}

__global__ __launch_bounds__(256) void huxley_kernel(
    const float* __restrict__ Pin, size_t plane, int S,
    float* __restrict__ dst,
    const float* __restrict__ sg, const float* __restrict__ dk,
    const float* __restrict__ pa, const float* __restrict__ pgam,
    const float* __restrict__ ptau, const float* __restrict__ pvel,
    const float* __restrict__ gp, const float* __restrict__ chi)
{
    __shared__ float2 A[1024];
    __shared__ float2 Bb[1024];
    __shared__ float sErg[1024];
    __shared__ float sAbs[516];
    __shared__ float2 tw[512];
    __shared__ float red[256];
    __shared__ float sG[516];

    const int tid = threadIdx.x;
    const int row = blockIdx.x;
    const float* pin = Pin + (size_t)row * 1024;
    float* uo = dst + (size_t)row * 1024;

    for (int m = tid; m < 512; m += 256) {
        float s, c;
        sincosf(6.283185307179586f * (float)m * (1.0f / 1024.0f), &s, &c);
        tw[m] = make_float2(c, s);
    }
    for (int k = tid; k < 513; k += 256)
        sG[k] = 1.0f / (1.0f + expf(-sg[k]));
    for (int i = tid; i < 1024; i += 256) {
        float s = 0.0f;
        for (int ss = 0; ss < S; ++ss) s += pin[(size_t)ss * plane + i];
        A[i] = make_float2(s, 0.0f);
    }
    __syncthreads();

    fft1024(A, tw, tid, false);

    for (int p = tid; p < 1024; p += 256) {
        int k = (int)(__brev((unsigned)p) >> 22);
        int m = (k <= 512) ? k : 1024 - k;
        float g = sG[m] * (1.0f / 1024.0f);
        Bb[p] = make_float2(A[p].x * g, A[p].y * g);
    }
    __syncthreads();
    fft1024(Bb, tw, tid, true);
    for (int i = tid; i < 1024; i += 256) sErg[i] = Bb[i].x;
    __syncthreads();

    const float vv = pvel[0];
    for (int p = tid; p < 1024; p += 256) {
        int k = (int)(__brev((unsigned)p) >> 22);
        int m = (k <= 512) ? k : 1024 - k;
        float omg = 1.0f - sG[m];
        float nx = A[p].x * omg, ny = A[p].y * omg;
        float ang = (k <= 512)
            ? (-6.283185307179586f * vv * (float)k * (1.0f / 1024.0f))
            : (6.283185307179586f * vv * (float)(1024 - k) * (1.0f / 1024.0f));
        float sn, cs;
        sincosf(ang, &sn, &cs);
        float yx = nx * cs - ny * sn;
        float yy = nx * sn + ny * cs;
        if (k < 512)       sAbs[k]   = sqrtf(nx * nx + ny * ny);
        else if (k == 512) sAbs[512] = fabsf(yx);
        Bb[p] = make_float2(yx * (1.0f / 1024.0f), yy * (1.0f / 1024.0f));
    }
    __syncthreads();
    fft1024(Bb, tw, tid, true);

    float loc = 0.0f;
    for (int i = tid; i < 1024; i += 256) { float x = Bb[i].x; loc += x * x; }
    float trc = block_reduce_sum(loc, red, tid);

    loc = 0.0f;
    for (int k = tid; k < 513; k += 256) loc += sAbs[k];
    float mean = block_reduce_sum(loc, red, tid) * (1.0f / 513.0f);

    loc = 0.0f;
    for (int k = tid; k < 513; k += 256) { float d = sAbs[k] - mean; loc += d * d; }
    float varsum = block_reduce_sum(loc, red, tid);

    loc = 3.4e38f;
    for (int k = tid; k < 513; k += 256) loc = fminf(loc, sAbs[k]);
    float lmin = block_reduce_min(loc, red, tid);

    float det_pas = varsum * (1.0f / 512.0f) + 1e-6f;
    float sd = sqrtf(det_pas);
    float denom = 2.0f * sd * sd * sd + 1e-8f;
    float c3 = (3.0f * gp[row] - trc / ptau[0]) / denom;
    c3 = fminf(fmaxf(c3, -0.999f), 0.999f);
    float ph = acosf(c3) * (1.0f / 3.0f);
    float amp = 2.0f * sqrtf(lmin * (1.0f / 3.0f) + 1e-8f);
    float nu = sqrtf(trc);
    float achi = fabsf(chi[row]);
    float cbest = 0.0f, ebest = -1.0f;
    #pragma unroll
    for (int kb = 0; kb < 3; ++kb) {
        float ck = amp * cosf(ph + 2.0943951023931953f * (float)kb) * expf(-achi * (float)kb);
        float ek = fabsf(ck) * nu;
        if (ek > ebest) { ebest = ek; cbest = ck; }
    }

    const float a = pa[0], gm = pgam[0];
    const float k0 = dk[0], k1 = dk[1], k2 = dk[2];
    for (int i = tid; i < 1024; i += 256) {
        float e = sErg[i];
        float l = (i > 0) ? sErg[i - 1] : 0.0f;
        float r = (i < 1023) ? sErg[i + 1] : 0.0f;
        float reac = e * (e - a) * (1.0f - e);
        float diff = k0 * l + k1 * e + k2 * r;
        float un = e + 0.1f * (reac + gm * diff);
        float s = un + cbest * Bb[i].x;
        uo[i] = s / (1.0f + expf(-s));
    }
}

// ---------------------------------------------------------------------------

extern "C" void kernel_launch(void* const* d_in, const int* in_sizes, int n_in,
                              void* d_out, int out_size, void* d_ws, size_t ws_size,
                              hipStream_t stream) {
    const float* c    = (const float*)d_in[0];
    const float* bw0  = (const float*)d_in[1];
    const float* sw0  = (const float*)d_in[2];
    const float* bw1  = (const float*)d_in[3];
    const float* sw1  = (const float*)d_in[4];
    const float* bw2  = (const float*)d_in[5];
    const float* sw2  = (const float*)d_in[6];
    const float* sg   = (const float*)d_in[7];
    const float* dk   = (const float*)d_in[8];
    const float* pa   = (const float*)d_in[9];
    const float* pgam = (const float*)d_in[10];
    const float* ptau = (const float*)d_in[11];
    const float* pvel = (const float*)d_in[12];
    const float* gp   = (const float*)d_in[13];
    const float* chi  = (const float*)d_in[14];

    const int B = 4096, NIN = 512, W = 1024, NOUT = 1024;
    const int KE0 = 19 * NIN, KE1 = 19 * W;
    const size_t MN = (size_t)B * W;
    const size_t BE = (size_t)W * KE1 * 2;      // Bexp bytes (39.85 MB)
    dim3 blk(256);

    // ---- pick (CH, S): 256-row m-tiles; {4096,4} -> grid 8x16x4 = 512 = 2/CU ----
    struct Cand { int CH, S; };
    const Cand cands[] = {
        {4096, 4}, {4096, 3}, {2048, 4}, {2048, 3}, {1024, 4},
        {512, 4}, {256, 4}
    };
    int CH = 0, S = 1;
    for (const auto& cd : cands) {
        size_t need = BE + (size_t)cd.CH * KE1 * 2 + (size_t)cd.S * MN * 4;
        if (need <= ws_size) { CH = cd.CH; S = cd.S; break; }
    }

    if (CH > 0) {
        f16* Bexp = (f16*)d_ws;
        float* P  = (float*)((char*)d_ws + BE);                // S planes of M x N fp32
        f16* Aexp = (f16*)((char*)d_ws + BE + (size_t)S * MN * 4);

        // ceil-split Kc (multiple of 32); kernel clamps last split
        const int Kc0 = ((KE0 / 32 + S - 1) / S) * 32;
        const int Kc1 = ((KE1 / 32 + S - 1) / S) * 32;

        // ---- layer 0: KIN=512 ----
        prep_b<<<(W * NIN) / 256, blk, 0, stream>>>(bw0, sw0, Bexp, NIN, 9);
        for (int r0 = 0; r0 < B; r0 += CH) {
            expand_sum_a<<<(CH * NIN) / 256, blk, 0, stream>>>(
                c + (size_t)r0 * NIN, 0, 1, Aexp, NIN, 9);
            gemm_mfma<<<dim3(W / 128, CH / 256, S), blk, 0, stream>>>(
                Aexp, Bexp, P + (size_t)r0 * W, KE0, Kc0, MN, W);
        }
        // ---- layer 1: KIN=1024 ----
        prep_b<<<(W * W) / 256, blk, 0, stream>>>(bw1, sw1, Bexp, W, 10);
        for (int r0 = 0; r0 < B; r0 += CH) {
            expand_sum_a<<<(CH * W) / 256, blk, 0, stream>>>(
                P + (size_t)r0 * W, MN, S, Aexp, W, 10);
            gemm_mfma<<<dim3(W / 128, CH / 256, S), blk, 0, stream>>>(
                Aexp, Bexp, P + (size_t)r0 * W, KE1, Kc1, MN, W);
        }
        // ---- layer 2 ----
        prep_b<<<(NOUT * W) / 256, blk, 0, stream>>>(bw2, sw2, Bexp, W, 10);
        for (int r0 = 0; r0 < B; r0 += CH) {
            expand_sum_a<<<(CH * W) / 256, blk, 0, stream>>>(
                P + (size_t)r0 * W, MN, S, Aexp, W, 10);
            gemm_mfma<<<dim3(NOUT / 128, CH / 256, S), blk, 0, stream>>>(
                Aexp, Bexp, P + (size_t)r0 * W, KE1, Kc1, MN, NOUT);
        }
        huxley_kernel<<<B, blk, 0, stream>>>(P, MN, S, (float*)d_out,
                                             sg, dk, pa, pgam, ptau, pvel, gp, chi);
    } else {
        // fallback: round-1 fp32 path (needs only 33.6 MB ws)
        float* fx0 = (float*)d_ws;
        float* fx1 = fx0 + (size_t)B * W;
        dim3 g0(W / 64, B / 64);
        kan_gemm<<<g0, blk, 0, stream>>>(c,   bw0, sw0, fx0, NIN, W);
        kan_gemm<<<g0, blk, 0, stream>>>(fx0, bw1, sw1, fx1, W,   W);
        dim3 g2(NOUT / 64, B / 64);
        kan_gemm<<<g2, blk, 0, stream>>>(fx1, bw2, sw2, (float*)d_out, W, NOUT);
        huxley_kernel<<<B, blk, 0, stream>>>((float*)d_out, 0, 1, (float*)d_out,
                                             sg, dk, pa, pgam, ptau, pvel, gp, chi);
    }
}